// Round 1
// baseline (1388.703 us; speedup 1.0000x reference)
//
#include <hip/hip_runtime.h>

#define C_ 256
#define D_ 56
#define N_ 64
#define M_ 3584     // N * 56 (rows per channel, same for both stages since H==W)
#define DD_ 3136    // 56*56
#define PL_ 200704  // per-channel plane = M_*D_ = N*H*W
#define NS_ITERS 16

__device__ __forceinline__ void fma44(float (&acc)[4][4], const float4 a, const float4 b) {
  acc[0][0]=fmaf(a.x,b.x,acc[0][0]); acc[0][1]=fmaf(a.x,b.y,acc[0][1]); acc[0][2]=fmaf(a.x,b.z,acc[0][2]); acc[0][3]=fmaf(a.x,b.w,acc[0][3]);
  acc[1][0]=fmaf(a.y,b.x,acc[1][0]); acc[1][1]=fmaf(a.y,b.y,acc[1][1]); acc[1][2]=fmaf(a.y,b.z,acc[1][2]); acc[1][3]=fmaf(a.y,b.w,acc[1][3]);
  acc[2][0]=fmaf(a.z,b.x,acc[2][0]); acc[2][1]=fmaf(a.z,b.y,acc[2][1]); acc[2][2]=fmaf(a.z,b.z,acc[2][2]); acc[2][3]=fmaf(a.z,b.w,acc[2][3]);
  acc[3][0]=fmaf(a.w,b.x,acc[3][0]); acc[3][1]=fmaf(a.w,b.y,acc[3][1]); acc[3][2]=fmaf(a.w,b.z,acc[3][2]); acc[3][3]=fmaf(a.w,b.w,acc[3][3]);
}

// x (N,H,W,C) -> A (C, n*W+w, h)   [stage-1 row layout, h contiguous]
__global__ __launch_bounds__(256) void k_tin(const float* __restrict__ x, float* __restrict__ A) {
  int b = blockIdx.x;
  int cchunk = b & 3, nw = b >> 2;
  int n = nw / 56, w = nw % 56;
  int c0 = cchunk * 64;
  __shared__ float t[56][65];
  int tid = threadIdx.x;
  const float* xp = x + ((size_t)n*3136 + w)*256 + c0;
  for (int i = tid; i < 56*64; i += 256) {
    int h = i >> 6, cc = i & 63;
    t[h][cc] = xp[(size_t)h*14336 + cc];
  }
  __syncthreads();
  float* Ap = A + (size_t)c0*PL_ + (size_t)nw*56;
  for (int i = tid; i < 64*56; i += 256) {
    int cc = i / 56, h = i % 56;
    Ap[(size_t)cc*PL_ + h] = t[h][cc];
  }
}

// partial column sums: in (C, M, 56) -> muPart[s][c][64]
__global__ __launch_bounds__(256) void k_mupart(const float* __restrict__ in, float* __restrict__ muPart) {
  int b = blockIdx.x;
  int c = b >> 3, s = b & 7;
  int tid = threadIdx.x;
  int grp = tid >> 6, lane = tid & 63;
  const float* p = in + (size_t)c*PL_ + (size_t)(s*448)*56;
  float acc = 0.f;
  if (lane < 56) {
    for (int m = grp; m < 448; m += 4) acc += p[m*56 + lane];
  }
  __shared__ float red[4][64];
  red[grp][lane] = acc;
  __syncthreads();
  if (tid < 64) {
    muPart[((size_t)s*C_ + c)*64 + lane] = red[0][lane]+red[1][lane]+red[2][lane]+red[3][lane];
  }
}

__global__ __launch_bounds__(256) void k_mured(const float* __restrict__ muPart, float* __restrict__ muT) {
  int idx = blockIdx.x*256 + threadIdx.x;
  if (idx >= C_*64) return;
  int c = idx >> 6, lane = idx & 63;
  float s = 0.f;
  for (int p = 0; p < 8; ++p) s += muPart[((size_t)p*C_ + c)*64 + lane];
  muT[idx] = s * (1.0f/M_);
}

// partial second moment of centered rows: covPart[s][c][56][56]
__global__ __launch_bounds__(256) void k_covpart(const float* __restrict__ in, const float* __restrict__ muT,
                                                 float* __restrict__ covPart) {
  int b = blockIdx.x;
  int c = b >> 3, s = b & 7;
  const float* p = in + (size_t)c*PL_ + (size_t)(s*448)*56;
  __shared__ __align__(16) float t[32][60];
  __shared__ float smu[56];
  int tid = threadIdx.x;
  if (tid < 56) smu[tid] = muT[c*64 + tid];
  __syncthreads();
  int ti = tid >> 4, tj = tid & 15;
  bool act = (ti < 14) && (tj < 14);
  int i0 = 4*ti, j0 = 4*tj;
  float acc[4][4] = {};
  for (int m0 = 0; m0 < 448; m0 += 32) {
    for (int i = tid; i < 32*56; i += 256) {
      int r = i / 56, d = i % 56;
      t[r][d] = p[(m0+r)*56 + d] - smu[d];
    }
    __syncthreads();
    if (act) {
      for (int kk = 0; kk < 32; ++kk) {
        float4 av = *(const float4*)&t[kk][i0];
        float4 bv = *(const float4*)&t[kk][j0];
        fma44(acc, av, bv);
      }
    }
    __syncthreads();
  }
  if (act) {
    float* op = covPart + ((size_t)s*C_ + c)*DD_;
    for (int r = 0; r < 4; ++r) {
      *(float4*)&op[(i0+r)*56 + j0] = make_float4(acc[r][0], acc[r][1], acc[r][2], acc[r][3]);
    }
  }
}

// covJ = (sum parts)/M with diagonal *1.001 jitter
__global__ __launch_bounds__(256) void k_covred(const float* __restrict__ covPart, float* __restrict__ covJ) {
  int idx = blockIdx.x*256 + threadIdx.x;
  if (idx >= C_*DD_) return;
  float s = 0.f;
  for (int p = 0; p < 8; ++p) s += covPart[(size_t)p*C_*DD_ + idx];
  int r2 = idx % DD_;
  int i = r2 / 56, j = r2 % 56;
  float v = s * (1.0f/M_);
  if (i == j) v *= 1.001f;
  covJ[idx] = v;
}

__global__ __launch_bounds__(256) void k_covtrain(const float* __restrict__ covIn, const float* __restrict__ muTr,
                                                  const int* __restrict__ counter, float* __restrict__ covTr) {
  int idx = blockIdx.x*256 + threadIdx.x;
  if (idx >= C_*DD_) return;
  int c = idx / DD_;
  int r2 = idx % DD_;
  int i = r2 / 56, j = r2 % 56;
  float cnt = (float)counter[0];
  covTr[idx] = covIn[idx] / cnt - muTr[c*56 + i] * muTr[c*56 + j];
}

// C = A@B for symmetric A,B (reads row-wise: C[i][j] = sum_k A[k][i]*B[k][j])
// tmode: C = 1.5I - 0.5*(A@B)
__device__ __forceinline__ void mm56(const float (*A)[60], const float (*B)[60], float (*Cm)[60],
                                     int tid, bool tmode) {
  int ti = tid >> 4, tj = tid & 15;
  if (ti < 14 && tj < 14) {
    int i0 = 4*ti, j0 = 4*tj;
    float acc[4][4] = {};
    #pragma unroll 4
    for (int k = 0; k < 56; ++k) {
      float4 av = *(const float4*)&A[k][i0];
      float4 bv = *(const float4*)&B[k][j0];
      fma44(acc, av, bv);
    }
    for (int r = 0; r < 4; ++r) {
      float4 o;
      if (tmode) {
        o.x = ((i0+r)==(j0+0) ? 1.5f : 0.f) - 0.5f*acc[r][0];
        o.y = ((i0+r)==(j0+1) ? 1.5f : 0.f) - 0.5f*acc[r][1];
        o.z = ((i0+r)==(j0+2) ? 1.5f : 0.f) - 0.5f*acc[r][2];
        o.w = ((i0+r)==(j0+3) ? 1.5f : 0.f) - 0.5f*acc[r][3];
      } else {
        o = make_float4(acc[r][0], acc[r][1], acc[r][2], acc[r][3]);
      }
      *(float4*)&Cm[i0+r][j0] = o;
    }
  }
}

// Coupled Newton-Schulz: which==0 -> sqrt(covTr) into S ; which==1 -> invsqrt(covJ) into Zi
__global__ __launch_bounds__(256) void k_ns(const float* __restrict__ covTr, const float* __restrict__ covJ,
                                            float* __restrict__ S, float* __restrict__ Zi) {
  __shared__ __align__(16) float buf[4][56][60];
  __shared__ float red[4];
  int tid = threadIdx.x;
  int which = blockIdx.x & 1, c = blockIdx.x >> 1;
  const float* Ain = (which ? covJ : covTr) + (size_t)c * DD_;
  float ss = 0.f;
  for (int i = tid; i < DD_; i += 256) {
    float v = Ain[i];
    buf[0][i/56][i%56] = v;
    ss += v*v;
  }
  #pragma unroll
  for (int off = 32; off > 0; off >>= 1) ss += __shfl_down(ss, off, 64);
  if ((tid & 63) == 0) red[tid >> 6] = ss;
  __syncthreads();
  float fro2 = red[0]+red[1]+red[2]+red[3];
  float s = sqrtf(fro2);
  float inv = 1.f / s;
  for (int i = tid; i < DD_; i += 256) {
    int r = i / 56, q = i % 56;
    buf[0][r][q] *= inv;
    buf[1][r][q] = (r == q) ? 1.f : 0.f;
  }
  __syncthreads();
  int bY = 0, bZ = 1, bT = 2, bU = 3;
  for (int it = 0; it < NS_ITERS; ++it) {
    mm56(buf[bZ], buf[bY], buf[bT], tid, true);    // T = 1.5I - 0.5*Z@Y
    __syncthreads();
    mm56(buf[bY], buf[bT], buf[bU], tid, false);   // Y' = Y@T
    __syncthreads();
    mm56(buf[bT], buf[bZ], buf[bY], tid, false);   // Z' = T@Z  (into old Y buffer)
    __syncthreads();
    int t0 = bY; bY = bU; bU = bZ; bZ = t0;
  }
  float rs = sqrtf(s);
  float fac = which ? (1.f/rs) : rs;
  const float (*src)[60] = which ? buf[bZ] : buf[bY];
  float* outp = (which ? Zi : S) + (size_t)c*DD_;
  for (int i = tid; i < DD_; i += 256) outp[i] = src[i/56][i%56] * fac;
}

// Tm[c] = Zi[c] @ S[c]   (both symmetric)
__global__ __launch_bounds__(256) void k_tmap(const float* __restrict__ Zi, const float* __restrict__ Sm,
                                              float* __restrict__ Tm) {
  __shared__ __align__(16) float a[56][60];
  __shared__ __align__(16) float b2[56][60];
  int c = blockIdx.x, tid = threadIdx.x;
  for (int i = tid; i < DD_; i += 256) {
    a[i/56][i%56]  = Zi[(size_t)c*DD_ + i];
    b2[i/56][i%56] = Sm[(size_t)c*DD_ + i];
  }
  __syncthreads();
  int ti = tid >> 4, tj = tid & 15;
  if (ti < 14 && tj < 14) {
    int i0 = 4*ti, j0 = 4*tj;
    float acc[4][4] = {};
    #pragma unroll 4
    for (int k = 0; k < 56; ++k) {
      float4 av = *(const float4*)&a[k][i0];
      float4 bv = *(const float4*)&b2[k][j0];
      fma44(acc, av, bv);
    }
    float* op = Tm + (size_t)c*DD_;
    for (int r = 0; r < 4; ++r) {
      *(float4*)&op[(i0+r)*56 + j0] = make_float4(acc[r][0], acc[r][1], acc[r][2], acc[r][3]);
    }
  }
}

// out_rows = (rows - muTest) @ Tm + muTrain ; write in next stage's layout
// stage 1: rows m=(n,w), col f=h -> out[c][n][h][w] ; stage 2: rows m=(n,h), col f=w -> out[c][n][h][w]
__global__ __launch_bounds__(256) void k_apply(const float* __restrict__ in, const float* __restrict__ muT,
                                               const float* __restrict__ Tmp, const float* __restrict__ muTrain,
                                               float* __restrict__ out, int stage) {
  int b = blockIdx.x;
  int c = b / 56, mb = b % 56;
  __shared__ __align__(16) float Tl[56][60];
  __shared__ __align__(16) float R[64][60];
  __shared__ float smu[56], smt[56];
  int tid = threadIdx.x;
  for (int i = tid; i < DD_; i += 256) Tl[i/56][i%56] = Tmp[(size_t)c*DD_ + i];
  if (tid < 56) { smu[tid] = muT[c*64 + tid]; smt[tid] = muTrain[c*56 + tid]; }
  __syncthreads();
  int m0 = mb * 64;
  const float* p = in + (size_t)c*PL_ + (size_t)m0*56;
  for (int i = tid; i < 64*56; i += 256) {
    int r = i / 56, d = i % 56;
    R[r][d] = p[r*56 + d] - smu[d];
  }
  __syncthreads();
  int ti = tid >> 4, tj = tid & 15;
  if (tj < 14) {
    int i0 = 4*ti, j0 = 4*tj;
    float acc[4][4] = {};
    for (int k = 0; k < 56; ++k) {
      float4 bv = *(const float4*)&Tl[k][j0];
      float4 av = make_float4(R[i0][k], R[i0+1][k], R[i0+2][k], R[i0+3][k]);
      fma44(acc, av, bv);
    }
    size_t cbase = (size_t)c * PL_;
    for (int r = 0; r < 4; ++r) {
      int m = m0 + i0 + r;
      int n = m / 56, rem = m % 56;
      size_t rowbase = cbase + (size_t)n * 3136;
      for (int q = 0; q < 4; ++q) {
        int f = j0 + q;
        float v = acc[r][q] + smt[f];
        size_t addr = (stage == 1) ? (rowbase + (size_t)f*56 + rem)
                                   : (rowbase + (size_t)rem*56 + f);
        out[addr] = v;
      }
    }
  }
}

// A2 (c, n, h, w) -> out (n, h, w, c)
__global__ __launch_bounds__(256) void k_tout(const float* __restrict__ A2, float* __restrict__ out) {
  int b = blockIdx.x;
  int cchunk = b & 3, nh = b >> 2;
  int c0 = cchunk * 64;
  __shared__ float t[64][57];
  int tid = threadIdx.x;
  const float* Ap = A2 + (size_t)c0*PL_ + (size_t)nh*56;
  for (int i = tid; i < 64*56; i += 256) {
    int cc = i / 56, w = i % 56;
    t[cc][w] = Ap[(size_t)cc*PL_ + w];
  }
  __syncthreads();
  float* op = out + (size_t)nh*56*256 + c0;
  for (int i = tid; i < 56*64; i += 256) {
    int w = i >> 6, cc = i & 63;
    op[(size_t)w*256 + cc] = t[cc][w];
  }
}

extern "C" void kernel_launch(void* const* d_in, const int* in_sizes, int n_in,
                              void* d_out, int out_size, void* d_ws, size_t ws_size,
                              hipStream_t stream) {
  (void)in_sizes; (void)n_in; (void)out_size;
  const float* x    = (const float*)d_in[0];
  const float* covH = (const float*)d_in[1];
  const float* muH  = (const float*)d_in[2];
  const float* covW = (const float*)d_in[3];
  const float* muW  = (const float*)d_in[4];
  const int*   cnt  = (const int*)d_in[5];
  float* out = (float*)d_out;

  char* ws = (char*)d_ws;
  size_t off = 0;
  auto alloc = [&](size_t nfloats) {
    float* p = (float*)(ws + off);
    off += ((nfloats*sizeof(float) + 255) / 256) * 256;
    return p;
  };
  float* A       = alloc((size_t)C_ * PL_);
  float* covPart = alloc((size_t)8 * C_ * DD_);
  float* muPart  = alloc((size_t)8 * C_ * 64);
  float* covJ    = alloc((size_t)C_ * DD_);
  float* covTr   = alloc((size_t)C_ * DD_);
  float* Sm      = alloc((size_t)C_ * DD_);
  float* Zim     = alloc((size_t)C_ * DD_);
  float* Tm      = alloc((size_t)C_ * DD_);
  float* muT     = alloc((size_t)C_ * 64);
  if (off > ws_size) return;  // workspace too small; bail

  dim3 blk(256);
  k_tin<<<dim3(14336), blk, 0, stream>>>(x, A);

  // ---- stage 1 (H axis) ----
  k_mupart  <<<dim3(2048),  blk, 0, stream>>>(A, muPart);
  k_mured   <<<dim3(64),    blk, 0, stream>>>(muPart, muT);
  k_covpart <<<dim3(2048),  blk, 0, stream>>>(A, muT, covPart);
  k_covred  <<<dim3(3136),  blk, 0, stream>>>(covPart, covJ);
  k_covtrain<<<dim3(3136),  blk, 0, stream>>>(covH, muH, cnt, covTr);
  k_ns      <<<dim3(512),   blk, 0, stream>>>(covTr, covJ, Sm, Zim);
  k_tmap    <<<dim3(256),   blk, 0, stream>>>(Zim, Sm, Tm);
  k_apply   <<<dim3(14336), blk, 0, stream>>>(A, muT, Tm, muH, out, 1);

  // ---- stage 2 (W axis) ----
  k_mupart  <<<dim3(2048),  blk, 0, stream>>>(out, muPart);
  k_mured   <<<dim3(64),    blk, 0, stream>>>(muPart, muT);
  k_covpart <<<dim3(2048),  blk, 0, stream>>>(out, muT, covPart);
  k_covred  <<<dim3(3136),  blk, 0, stream>>>(covPart, covJ);
  k_covtrain<<<dim3(3136),  blk, 0, stream>>>(covW, muW, cnt, covTr);
  k_ns      <<<dim3(512),   blk, 0, stream>>>(covTr, covJ, Sm, Zim);
  k_tmap    <<<dim3(256),   blk, 0, stream>>>(Zim, Sm, Tm);
  k_apply   <<<dim3(14336), blk, 0, stream>>>(out, muT, Tm, muW, A, 2);

  k_tout<<<dim3(14336), blk, 0, stream>>>(A, out);
}

// Round 2
// 1086.102 us; speedup vs baseline: 1.2786x; 1.2786x over previous
//
#include <hip/hip_runtime.h>

#define C_ 256
#define D_ 56
#define N_ 64
#define M_ 3584     // rows per channel (N*56), same both stages since H==W
#define DD_ 3136    // 56*56
#define PL_ 200704  // per-channel plane = M_*56
#define NS_ITERS 16

typedef __attribute__((ext_vector_type(8))) short v8s;
typedef __attribute__((ext_vector_type(4))) float v4f;

__device__ __forceinline__ unsigned short f2bf(float f) {
  union { float f; unsigned u; } x; x.f = f;
  unsigned r = x.u + 0x7FFFu + ((x.u >> 16) & 1u);
  return (unsigned short)(r >> 16);
}
__device__ __forceinline__ float bf2f(unsigned short h) {
  union { unsigned u; float f; } x; x.u = ((unsigned)h) << 16;
  return x.f;
}

__device__ __forceinline__ void fma44(float (&acc)[4][4], const float4 a, const float4 b) {
  acc[0][0]=fmaf(a.x,b.x,acc[0][0]); acc[0][1]=fmaf(a.x,b.y,acc[0][1]); acc[0][2]=fmaf(a.x,b.z,acc[0][2]); acc[0][3]=fmaf(a.x,b.w,acc[0][3]);
  acc[1][0]=fmaf(a.y,b.x,acc[1][0]); acc[1][1]=fmaf(a.y,b.y,acc[1][1]); acc[1][2]=fmaf(a.y,b.z,acc[1][2]); acc[1][3]=fmaf(a.y,b.w,acc[1][3]);
  acc[2][0]=fmaf(a.z,b.x,acc[2][0]); acc[2][1]=fmaf(a.z,b.y,acc[2][1]); acc[2][2]=fmaf(a.z,b.z,acc[2][2]); acc[2][3]=fmaf(a.z,b.w,acc[2][3]);
  acc[3][0]=fmaf(a.w,b.x,acc[3][0]); acc[3][1]=fmaf(a.w,b.y,acc[3][1]); acc[3][2]=fmaf(a.w,b.z,acc[3][2]); acc[3][3]=fmaf(a.w,b.w,acc[3][3]);
}

// x (N,H,W,C) -> A (C, n*56+w, h)
__global__ __launch_bounds__(256) void k_tin(const float* __restrict__ x, float* __restrict__ A) {
  int b = blockIdx.x;
  int cchunk = b & 3, nw = b >> 2;
  int n = nw / 56, w = nw % 56;
  int c0 = cchunk * 64;
  __shared__ float t[56][65];
  int tid = threadIdx.x;
  const float* xp = x + ((size_t)n*3136 + w)*256 + c0;
  for (int i = tid; i < 56*64; i += 256) {
    int h = i >> 6, cc = i & 63;
    t[h][cc] = xp[(size_t)h*14336 + cc];
  }
  __syncthreads();
  float* Ap = A + (size_t)c0*PL_ + (size_t)nw*56;
  for (int i = tid; i < 64*56; i += 256) {
    int cc = i / 56, h = i % 56;
    Ap[(size_t)cc*PL_ + h] = t[h][cc];
  }
}

// Fused: raw column-sum partials + raw second moment via split-bf16 MFMA.
// in: (C, 3584, 56) row-major tiles. out: muPart[s][c][64], covPart[(s*C+c)][56*56]
__global__ __launch_bounds__(256) void k_stats(const float* __restrict__ in,
                                               float* __restrict__ muPart,
                                               float* __restrict__ covPart) {
  int b = blockIdx.x;
  int c = b >> 3, s = b & 7;
  const float* p = in + (size_t)c*PL_ + (size_t)(s*448)*56;
  __shared__ __align__(16) char lds[2*64*72*2];            // 18432 B
  unsigned short (*At)[72]  = (unsigned short(*)[72])lds;          // Ah transposed [k][m]
  unsigned short (*Alt)[72] = (unsigned short(*)[72])(lds + 9216); // Al transposed [k][m]
  float (*Qbuf)[66] = (float(*)[66])lds;                           // epilogue overlay (16896 B)
  __shared__ float red[4][64];
  int tid = threadIdx.x;

  // ---- column-sum prologue (fp32 exact) ----
  {
    int grp = tid >> 6, lane = tid & 63;
    float acc = 0.f;
    if (lane < 56) {
      for (int m = grp; m < 448; m += 4) acc += p[m*56 + lane];
    }
    red[grp][lane] = acc;
    __syncthreads();
    if (tid < 64)
      muPart[((size_t)s*C_ + c)*64 + tid] = red[0][tid]+red[1][tid]+red[2][tid]+red[3][tid];
  }

  int l = tid & 63, w = tid >> 6;
  int lr = l & 15, lq = l >> 4;
  v4f zero4 = {0.f, 0.f, 0.f, 0.f};
  v4f accP[4], accQ[4];
  #pragma unroll
  for (int j = 0; j < 4; ++j) { accP[j] = zero4; accQ[j] = zero4; }

  for (int ch = 0; ch < 7; ++ch) {
    __syncthreads();
    const float4* p4 = (const float4*)(p + ch*64*56);
    for (int i = tid; i < 896; i += 256) {
      float4 v = p4[i];
      int row = i / 14, cg = (i % 14) * 4;
      float vv0 = v.x, vv1 = v.y, vv2 = v.z, vv3 = v.w;
      unsigned short ah;
      ah = f2bf(vv0); At[cg+0][row] = ah; Alt[cg+0][row] = f2bf(vv0 - bf2f(ah));
      ah = f2bf(vv1); At[cg+1][row] = ah; Alt[cg+1][row] = f2bf(vv1 - bf2f(ah));
      ah = f2bf(vv2); At[cg+2][row] = ah; Alt[cg+2][row] = f2bf(vv2 - bf2f(ah));
      ah = f2bf(vv3); At[cg+3][row] = ah; Alt[cg+3][row] = f2bf(vv3 - bf2f(ah));
    }
    __syncthreads();
    #pragma unroll
    for (int s2 = 0; s2 < 2; ++s2) {
      int kb = 32*s2 + 8*lq;
      v8s a = *(const v8s*)&At[16*w + lr][kb];
      #pragma unroll
      for (int j = 0; j < 4; ++j) {
        v8s bh = *(const v8s*)&At[16*j + lr][kb];
        v8s bl = *(const v8s*)&Alt[16*j + lr][kb];
        accP[j] = __builtin_amdgcn_mfma_f32_16x16x32_bf16(a, bh, accP[j], 0, 0, 0);
        accQ[j] = __builtin_amdgcn_mfma_f32_16x16x32_bf16(a, bl, accQ[j], 0, 0, 0);
      }
    }
  }

  // ---- epilogue: S = P + Q + Q^T ----
  __syncthreads();
  #pragma unroll
  for (int j = 0; j < 4; ++j) {
    #pragma unroll
    for (int e = 0; e < 4; ++e) {
      int r = 16*w + 4*lq + e, cc = 16*j + lr;
      Qbuf[r][cc] = accQ[j][e];
    }
  }
  __syncthreads();
  float* op = covPart + ((size_t)s*C_ + c)*DD_;
  #pragma unroll
  for (int j = 0; j < 4; ++j) {
    #pragma unroll
    for (int e = 0; e < 4; ++e) {
      int r = 16*w + 4*lq + e, cc = 16*j + lr;
      if (r < 56 && cc < 56) op[r*56 + cc] = accP[j][e] + accQ[j][e] + Qbuf[cc][r];
    }
  }
}

__global__ __launch_bounds__(256) void k_mured(const float* __restrict__ muPart, float* __restrict__ muT) {
  int idx = blockIdx.x*256 + threadIdx.x;
  if (idx >= C_*64) return;
  int c = idx >> 6, lane = idx & 63;
  float s = 0.f;
  for (int p = 0; p < 8; ++p) s += muPart[((size_t)p*C_ + c)*64 + lane];
  muT[idx] = s * (1.0f/M_);
}

// test cov (from parts + mu, jittered) AND train cov (from covIn + muTrain + counter)
__global__ __launch_bounds__(256) void k_finalize(const float* __restrict__ covPart, const float* __restrict__ muT,
                                                  const float* __restrict__ covIn, const float* __restrict__ muTrn,
                                                  const int* __restrict__ counter,
                                                  float* __restrict__ covTest, float* __restrict__ covTr) {
  int idx = blockIdx.x*256 + threadIdx.x;
  const int total = C_*DD_;
  if (idx < total) {
    int c = idx / DD_, r2 = idx % DD_, i = r2/56, j = r2%56;
    float ssum = 0.f;
    for (int s = 0; s < 8; ++s) ssum += covPart[((size_t)s*C_ + c)*DD_ + r2];
    float v = ssum*(1.0f/M_) - muT[c*64+i]*muT[c*64+j];
    if (i == j) v *= 1.001f;
    covTest[idx] = v;
  } else if (idx < 2*total) {
    int k = idx - total;
    int c = k / DD_, r2 = k % DD_, i = r2/56, j = r2%56;
    float cnt = (float)counter[0];
    covTr[k] = covIn[k]/cnt - muTrn[c*56+i]*muTrn[c*56+j];
  }
}

// symmetric 56x56 matmul, triangle-mapped (waves 2,3 idle): Cm = A@B (or 1.5I-0.5A@B)
__device__ __forceinline__ void mm56t(const float (*A)[60], const float (*B)[60], float (*Cm)[60],
                                      bool act, int i0, int j0, bool tmode) {
  if (act) {
    float acc[4][4] = {};
    #pragma unroll 4
    for (int k = 0; k < 56; ++k) {
      float4 av = *(const float4*)&A[k][i0];
      float4 bv = *(const float4*)&B[k][j0];
      fma44(acc, av, bv);
    }
    #pragma unroll
    for (int r = 0; r < 4; ++r) {
      #pragma unroll
      for (int q = 0; q < 4; ++q) {
        float v = tmode ? (((i0+r)==(j0+q) ? 1.5f : 0.f) - 0.5f*acc[r][q]) : acc[r][q];
        Cm[i0+r][j0+q] = v;
        if (i0 != j0) Cm[j0+q][i0+r] = v;
      }
    }
  }
}

// Coupled Newton-Schulz: which==0 -> sqrt(covTr) into S ; which==1 -> invsqrt(covTest) into Zi
__global__ __launch_bounds__(256) void k_ns(const float* __restrict__ covTr, const float* __restrict__ covTest,
                                            float* __restrict__ S, float* __restrict__ Zi) {
  __shared__ __align__(16) float buf[4][56][60];
  __shared__ float red[4];
  int tid = threadIdx.x;
  int which = blockIdx.x & 1, c = blockIdx.x >> 1;
  const float* Ain = (which ? covTest : covTr) + (size_t)c * DD_;
  float ss = 0.f;
  for (int i = tid; i < DD_; i += 256) {
    float v = Ain[i];
    buf[0][i/56][i%56] = v;
    ss += v*v;
  }
  #pragma unroll
  for (int off = 32; off > 0; off >>= 1) ss += __shfl_down(ss, off, 64);
  if ((tid & 63) == 0) red[tid >> 6] = ss;
  __syncthreads();
  float fro2 = red[0]+red[1]+red[2]+red[3];
  float s = sqrtf(fro2);
  float inv = 1.f / s;
  for (int i = tid; i < DD_; i += 256) {
    int r = i / 56, q = i % 56;
    buf[0][r][q] *= inv;
    buf[1][r][q] = (r == q) ? 1.f : 0.f;
  }
  // triangle mapping: tid -> upper 4x4 block (bi,bj)
  bool act = tid < 105;
  int bi = 0, rem = tid;
  if (act) { while (rem >= 14 - bi) { rem -= 14 - bi; bi++; } }
  int i0 = 4*bi, j0 = 4*(bi + rem);
  __syncthreads();
  int bY = 0, bZ = 1, bT = 2, bU = 3;
  for (int it = 0; it < NS_ITERS; ++it) {
    mm56t(buf[bZ], buf[bY], buf[bT], act, i0, j0, true);    // T = 1.5I - 0.5*Z@Y
    __syncthreads();
    mm56t(buf[bY], buf[bT], buf[bU], act, i0, j0, false);   // Y' = Y@T
    __syncthreads();
    mm56t(buf[bT], buf[bZ], buf[bY], act, i0, j0, false);   // Z' = T@Z
    __syncthreads();
    int t0 = bY; bY = bU; bU = bZ; bZ = t0;
  }
  float rs = sqrtf(s);
  float fac = which ? (1.f/rs) : rs;
  const float (*src)[60] = which ? buf[bZ] : buf[bY];
  float* outp = (which ? Zi : S) + (size_t)c*DD_;
  for (int i = tid; i < DD_; i += 256) outp[i] = src[i/56][i%56] * fac;
}

// Tm[c] = Zi[c] @ S[c]
__global__ __launch_bounds__(256) void k_tmap(const float* __restrict__ Zi, const float* __restrict__ Sm,
                                              float* __restrict__ Tm) {
  __shared__ __align__(16) float a[56][60];
  __shared__ __align__(16) float b2[56][60];
  int c = blockIdx.x, tid = threadIdx.x;
  for (int i = tid; i < DD_; i += 256) {
    a[i/56][i%56]  = Zi[(size_t)c*DD_ + i];
    b2[i/56][i%56] = Sm[(size_t)c*DD_ + i];
  }
  __syncthreads();
  int ti = tid >> 4, tj = tid & 15;
  if (ti < 14 && tj < 14) {
    int i0 = 4*ti, j0 = 4*tj;
    float acc[4][4] = {};
    #pragma unroll 4
    for (int k = 0; k < 56; ++k) {
      float4 av = *(const float4*)&a[k][i0];
      float4 bv = *(const float4*)&b2[k][j0];
      fma44(acc, av, bv);
    }
    float* op = Tm + (size_t)c*DD_;
    for (int r = 0; r < 4; ++r)
      *(float4*)&op[(i0+r)*56 + j0] = make_float4(acc[r][0], acc[r][1], acc[r][2], acc[r][3]);
  }
}

// Per-(c,n) 56x56 tile: Y = (X - muT) @ T + muTrain via bf16 MFMA, fp32 accum.
// stage 1: input tile rows=w cols=h, write out[c][n][h][w] (transposed tile)
// stage 2: input tile rows=h cols=w, write out[c][n][h][w] (direct tile)
__global__ __launch_bounds__(256) void k_apply(const float* __restrict__ in, const float* __restrict__ muT,
                                               const float* __restrict__ Tmp, const float* __restrict__ muTrain,
                                               float* __restrict__ out, int stage) {
  int b = blockIdx.x;
  int c = b >> 6, n = b & 63;
  __shared__ __align__(16) char lds[2*64*72*2];            // 18432 B
  unsigned short (*Abf)[72] = (unsigned short(*)[72])lds;          // centered rows bf16 [m][k]
  unsigned short (*Tt)[72]  = (unsigned short(*)[72])(lds + 9216); // T transposed bf16 [f][k]
  float (*Y)[66] = (float(*)[66])lds;                              // epilogue overlay
  __shared__ float smu[64], smt[64];
  int tid = threadIdx.x;
  if (tid < 64) {
    smu[tid] = muT[c*64 + tid];
    smt[tid] = (tid < 56) ? muTrain[c*56 + tid] : 0.f;
  }
  {
    unsigned* za = (unsigned*)lds;   // zero both tiles (K padding must be 0)
    for (int i = tid; i < 2*2304; i += 256) za[i] = 0u;
  }
  __syncthreads();
  const float4* p4 = (const float4*)(in + (size_t)c*PL_ + (size_t)n*3136);
  const float4* t4 = (const float4*)(Tmp + (size_t)c*DD_);
  for (int i = tid; i < 784; i += 256) {
    float4 v = p4[i];
    int row = i / 14, cg = (i % 14) * 4;
    ushort4 pk;
    pk.x = f2bf(v.x - smu[cg+0]);
    pk.y = f2bf(v.y - smu[cg+1]);
    pk.z = f2bf(v.z - smu[cg+2]);
    pk.w = f2bf(v.w - smu[cg+3]);
    *(ushort4*)&Abf[row][cg] = pk;
    float4 t = t4[i];
    Tt[cg+0][row] = f2bf(t.x);
    Tt[cg+1][row] = f2bf(t.y);
    Tt[cg+2][row] = f2bf(t.z);
    Tt[cg+3][row] = f2bf(t.w);
  }
  __syncthreads();
  int l = tid & 63, w = tid >> 6;
  int lr = l & 15, lq = l >> 4;
  v4f zero4 = {0.f, 0.f, 0.f, 0.f};
  v4f acc[4];
  #pragma unroll
  for (int j = 0; j < 4; ++j) acc[j] = zero4;
  #pragma unroll
  for (int s = 0; s < 2; ++s) {
    int kb = 32*s + 8*lq;
    v8s a = *(const v8s*)&Abf[16*w + lr][kb];
    #pragma unroll
    for (int j = 0; j < 4; ++j) {
      v8s bb = *(const v8s*)&Tt[16*j + lr][kb];
      acc[j] = __builtin_amdgcn_mfma_f32_16x16x32_bf16(a, bb, acc[j], 0, 0, 0);
    }
  }
  __syncthreads();   // done reading tiles; overlay Y
  #pragma unroll
  for (int j = 0; j < 4; ++j) {
    #pragma unroll
    for (int e = 0; e < 4; ++e) {
      int r = 16*w + 4*lq + e, cc = 16*j + lr;
      Y[r][cc] = acc[j][e] + smt[cc];
    }
  }
  __syncthreads();
  float* op = out + (size_t)c*PL_ + (size_t)n*3136;
  if (stage == 1) {
    for (int i = tid; i < 3136; i += 256) { int h = i/56, ww = i%56; op[i] = Y[ww][h]; }
  } else {
    for (int i = tid; i < 3136; i += 256) { int h = i/56, ww = i%56; op[i] = Y[h][ww]; }
  }
}

// A2 (c, n, h, w) -> out (n, h, w, c)
__global__ __launch_bounds__(256) void k_tout(const float* __restrict__ A2, float* __restrict__ out) {
  int b = blockIdx.x;
  int cchunk = b & 3, nh = b >> 2;
  int c0 = cchunk * 64;
  __shared__ float t[64][57];
  int tid = threadIdx.x;
  const float* Ap = A2 + (size_t)c0*PL_ + (size_t)nh*56;
  for (int i = tid; i < 64*56; i += 256) {
    int cc = i / 56, w = i % 56;
    t[cc][w] = Ap[(size_t)cc*PL_ + w];
  }
  __syncthreads();
  float* op = out + (size_t)nh*56*256 + c0;
  for (int i = tid; i < 56*64; i += 256) {
    int w = i >> 6, cc = i & 63;
    op[(size_t)w*256 + cc] = t[cc][w];
  }
}

extern "C" void kernel_launch(void* const* d_in, const int* in_sizes, int n_in,
                              void* d_out, int out_size, void* d_ws, size_t ws_size,
                              hipStream_t stream) {
  (void)in_sizes; (void)n_in; (void)out_size;
  const float* x    = (const float*)d_in[0];
  const float* covH = (const float*)d_in[1];
  const float* muH  = (const float*)d_in[2];
  const float* covW = (const float*)d_in[3];
  const float* muW  = (const float*)d_in[4];
  const int*   cnt  = (const int*)d_in[5];
  float* out = (float*)d_out;

  char* ws = (char*)d_ws;
  size_t off = 0;
  auto alloc = [&](size_t nfloats) {
    float* p = (float*)(ws + off);
    off += ((nfloats*sizeof(float) + 255) / 256) * 256;
    return p;
  };
  float* A       = alloc((size_t)C_ * PL_);
  float* covPart = alloc((size_t)8 * C_ * DD_);
  float* muPart  = alloc((size_t)8 * C_ * 64);
  float* covTest = alloc((size_t)C_ * DD_);
  float* covTr   = alloc((size_t)C_ * DD_);
  float* Sm      = alloc((size_t)C_ * DD_);
  float* Zim     = alloc((size_t)C_ * DD_);
  float* Tm      = alloc((size_t)C_ * DD_);
  float* muT     = alloc((size_t)C_ * 64);
  if (off > ws_size) return;

  dim3 blk(256);
  const int finGrid = (2*C_*DD_ + 255)/256;

  k_tin<<<dim3(14336), blk, 0, stream>>>(x, A);

  // ---- stage 1 (H axis) ----
  k_stats   <<<dim3(2048),  blk, 0, stream>>>(A, muPart, covPart);
  k_mured   <<<dim3(64),    blk, 0, stream>>>(muPart, muT);
  k_finalize<<<dim3(finGrid), blk, 0, stream>>>(covPart, muT, covH, muH, cnt, covTest, covTr);
  k_ns      <<<dim3(512),   blk, 0, stream>>>(covTr, covTest, Sm, Zim);
  k_tmap    <<<dim3(256),   blk, 0, stream>>>(Zim, Sm, Tm);
  k_apply   <<<dim3(16384), blk, 0, stream>>>(A, muT, Tm, muH, out, 1);

  // ---- stage 2 (W axis) ----
  k_stats   <<<dim3(2048),  blk, 0, stream>>>(out, muPart, covPart);
  k_mured   <<<dim3(64),    blk, 0, stream>>>(muPart, muT);
  k_finalize<<<dim3(finGrid), blk, 0, stream>>>(covPart, muT, covW, muW, cnt, covTest, covTr);
  k_ns      <<<dim3(512),   blk, 0, stream>>>(covTr, covTest, Sm, Zim);
  k_tmap    <<<dim3(256),   blk, 0, stream>>>(Zim, Sm, Tm);
  k_apply   <<<dim3(16384), blk, 0, stream>>>(out, muT, Tm, muW, A, 2);

  k_tout<<<dim3(14336), blk, 0, stream>>>(A, out);
}

// Round 4
// 657.568 us; speedup vs baseline: 2.1119x; 1.6517x over previous
//
#include <hip/hip_runtime.h>

#define C_ 256
#define D_ 56
#define N_ 64
#define M_ 3584     // rows per channel (N*56), same both stages since H==W
#define DD_ 3136    // 56*56
#define PL_ 200704  // per-channel plane = M_*56
#define NS_ITERS 16

typedef __attribute__((ext_vector_type(8))) short v8s;
typedef __attribute__((ext_vector_type(8))) _Float16 v8h;
typedef __attribute__((ext_vector_type(4))) _Float16 v4h;
typedef __attribute__((ext_vector_type(4))) float v4f;

__device__ __forceinline__ unsigned short f2bf(float f) {
  union { float f; unsigned u; } x; x.f = f;
  unsigned r = x.u + 0x7FFFu + ((x.u >> 16) & 1u);
  return (unsigned short)(r >> 16);
}
__device__ __forceinline__ float bf2f(unsigned short h) {
  union { unsigned u; float f; } x; x.u = ((unsigned)h) << 16;
  return x.f;
}

// x (N,H,W,C) -> A (C, n*56+w, h)
__global__ __launch_bounds__(256) void k_tin(const float* __restrict__ x, float* __restrict__ A) {
  int b = blockIdx.x;
  int cchunk = b & 3, nw = b >> 2;
  int n = nw / 56, w = nw % 56;
  int c0 = cchunk * 64;
  __shared__ float t[56][65];
  int tid = threadIdx.x;
  const float* xp = x + ((size_t)n*3136 + w)*256 + c0;
  for (int i = tid; i < 56*64; i += 256) {
    int h = i >> 6, cc = i & 63;
    t[h][cc] = xp[(size_t)h*14336 + cc];
  }
  __syncthreads();
  float* Ap = A + (size_t)c0*PL_ + (size_t)nw*56;
  for (int i = tid; i < 64*56; i += 256) {
    int cc = i / 56, h = i % 56;
    Ap[(size_t)cc*PL_ + h] = t[h][cc];
  }
}

// ---------- fp16-split MFMA helpers (2-way split: ~2^-22 effective precision) ----------
// acc[jt] += C where C[i][j] = sum_k (Ah+Al)[i][k] * (Bh+Bl)[j][k]  (Al*Bl dropped)
// i = 16*w + 4*lq + e, j = 16*jt + lr
__device__ __forceinline__ void mm_split_h(const _Float16 (*Ah)[72], const _Float16 (*Al)[72],
                                           const _Float16 (*Bh)[72], const _Float16 (*Bl)[72],
                                           int w, int lr, int lq, v4f (&acc)[4]) {
  v8h ah[2], al[2], bh[4][2], bl[4][2];
  #pragma unroll
  for (int s = 0; s < 2; ++s) {
    int kb = 32*s + 8*lq;
    ah[s] = *(const v8h*)&Ah[16*w + lr][kb];
    al[s] = *(const v8h*)&Al[16*w + lr][kb];
    #pragma unroll
    for (int jt = 0; jt < 4; ++jt) {
      bh[jt][s] = *(const v8h*)&Bh[16*jt + lr][kb];
      bl[jt][s] = *(const v8h*)&Bl[16*jt + lr][kb];
    }
  }
  #pragma unroll
  for (int jt = 0; jt < 4; ++jt) {
    #pragma unroll
    for (int s = 0; s < 2; ++s) {
      acc[jt] = __builtin_amdgcn_mfma_f32_16x16x32_f16(ah[s], bh[jt][s], acc[jt], 0, 0, 0);
      acc[jt] = __builtin_amdgcn_mfma_f32_16x16x32_f16(ah[s], bl[jt][s], acc[jt], 0, 0, 0);
      acc[jt] = __builtin_amdgcn_mfma_f32_16x16x32_f16(al[s], bh[jt][s], acc[jt], 0, 0, 0);
    }
  }
}

__device__ __forceinline__ void store_split_h(_Float16 (*H)[72], _Float16 (*L)[72],
                                              int w, int lr, int lq, const v4f (&val)[4]) {
  #pragma unroll
  for (int jt = 0; jt < 4; ++jt) {
    #pragma unroll
    for (int e = 0; e < 4; ++e) {
      int i = 16*w + 4*lq + e, j = 16*jt + lr;
      float v = val[jt][e];
      _Float16 h = (_Float16)v;
      H[i][j] = h;
      L[i][j] = (_Float16)(v - (float)h);
    }
  }
}

// Fused: raw column-sum (fp32 exact, in-register) + raw second moment via split-bf16 MFMA.
// (bf16-split is fine here: cov error gets divided by M=3584 -> ~1e-7 abs)
// in: (C, 3584, 56). out: muPart[s][c][64], covPart[(s*C+c)][56*56]
__global__ __launch_bounds__(256) void k_stats(const float* __restrict__ in,
                                               float* __restrict__ muPart,
                                               float* __restrict__ covPart) {
  int b = blockIdx.x;
  int c = b >> 3, s = b & 7;
  const float* p = in + (size_t)c*PL_ + (size_t)(s*448)*56;
  __shared__ __align__(16) char lds[18432];
  unsigned short (*At)[72]  = (unsigned short(*)[72])lds;          // Ah transposed [d][m]
  unsigned short (*Alt)[72] = (unsigned short(*)[72])(lds + 9216); // Al transposed [d][m]
  float (*Qbuf)[66] = (float(*)[66])lds;                           // epilogue overlay
  float (*red2)[60] = (float(*)[60])lds;                           // mu-reduction overlay
  int tid = threadIdx.x;
  int cg = tid % 14, rg = tid / 14;     // column-group / row-group (valid tid<224)
  bool act = tid < 224;
  float4 colsum = make_float4(0.f, 0.f, 0.f, 0.f);

  int l = tid & 63, w = tid >> 6;
  int lr = l & 15, lq = l >> 4;
  v4f zero4 = {0.f, 0.f, 0.f, 0.f};
  v4f accP[4], accQ[4];
  #pragma unroll
  for (int j = 0; j < 4; ++j) { accP[j] = zero4; accQ[j] = zero4; }

  for (int ch = 0; ch < 7; ++ch) {
    __syncthreads();
    const float4* p4 = (const float4*)(p + ch*64*56);
    if (act) {
      int c4 = cg * 4;
      #pragma unroll
      for (int u = 0; u < 4; ++u) {
        int m = u*16 + rg;
        float4 v = p4[m*14 + cg];
        colsum.x += v.x; colsum.y += v.y; colsum.z += v.z; colsum.w += v.w;
        unsigned short h;
        h = f2bf(v.x); At[c4+0][m] = h; Alt[c4+0][m] = f2bf(v.x - bf2f(h));
        h = f2bf(v.y); At[c4+1][m] = h; Alt[c4+1][m] = f2bf(v.y - bf2f(h));
        h = f2bf(v.z); At[c4+2][m] = h; Alt[c4+2][m] = f2bf(v.z - bf2f(h));
        h = f2bf(v.w); At[c4+3][m] = h; Alt[c4+3][m] = f2bf(v.w - bf2f(h));
      }
    }
    __syncthreads();
    #pragma unroll
    for (int s2 = 0; s2 < 2; ++s2) {
      int kb = 32*s2 + 8*lq;
      v8s a = *(const v8s*)&At[16*w + lr][kb];
      #pragma unroll
      for (int j = 0; j < 4; ++j) {
        v8s bh = *(const v8s*)&At[16*j + lr][kb];
        v8s bl = *(const v8s*)&Alt[16*j + lr][kb];
        accP[j] = __builtin_amdgcn_mfma_f32_16x16x32_bf16(a, bh, accP[j], 0, 0, 0);
        accQ[j] = __builtin_amdgcn_mfma_f32_16x16x32_bf16(a, bl, accQ[j], 0, 0, 0);
      }
    }
  }

  // ---- mu reduction (overlay on At region; MFMA reads are done) ----
  __syncthreads();
  if (act) *(float4*)&red2[rg][cg*4] = colsum;
  __syncthreads();
  if (tid < 64) {
    float m = 0.f;
    if (tid < 56) {
      #pragma unroll
      for (int r = 0; r < 16; ++r) m += red2[r][tid];
    }
    muPart[((size_t)s*C_ + c)*64 + tid] = m;   // cols 56..63 = 0
  }
  __syncthreads();

  // ---- epilogue: S = P + Q + Q^T ----
  #pragma unroll
  for (int j = 0; j < 4; ++j) {
    #pragma unroll
    for (int e = 0; e < 4; ++e) {
      int r = 16*w + 4*lq + e, cc = 16*j + lr;
      Qbuf[r][cc] = accQ[j][e];
    }
  }
  __syncthreads();
  float* op = covPart + ((size_t)s*C_ + c)*DD_;
  #pragma unroll
  for (int j = 0; j < 4; ++j) {
    #pragma unroll
    for (int e = 0; e < 4; ++e) {
      int r = 16*w + 4*lq + e, cc = 16*j + lr;
      if (r < 56 && cc < 56) op[r*56 + cc] = accP[j][e] + accQ[j][e] + Qbuf[cc][r];
    }
  }
}

__global__ __launch_bounds__(256) void k_mured(const float* __restrict__ muPart, float* __restrict__ muT) {
  int idx = blockIdx.x*256 + threadIdx.x;
  if (idx >= C_*64) return;
  int c = idx >> 6, lane = idx & 63;
  float s = 0.f;
  for (int p = 0; p < 8; ++p) s += muPart[((size_t)p*C_ + c)*64 + lane];
  muT[idx] = s * (1.0f/M_);
}

// test cov (from parts + mu, jittered) AND train cov (from covIn + muTrain + counter)
__global__ __launch_bounds__(256) void k_finalize(const float* __restrict__ covPart, const float* __restrict__ muT,
                                                  const float* __restrict__ covIn, const float* __restrict__ muTrn,
                                                  const int* __restrict__ counter,
                                                  float* __restrict__ covTest, float* __restrict__ covTr) {
  int idx = blockIdx.x*256 + threadIdx.x;
  const int total = C_*DD_;
  if (idx < total) {
    int c = idx / DD_, r2 = idx % DD_, i = r2/56, j = r2%56;
    float ssum = 0.f;
    for (int s = 0; s < 8; ++s) ssum += covPart[((size_t)s*C_ + c)*DD_ + r2];
    float v = ssum*(1.0f/M_) - muT[c*64+i]*muT[c*64+j];
    if (i == j) v *= 1.001f;
    covTest[idx] = v;
  } else if (idx < 2*total) {
    int k = idx - total;
    int c = k / DD_, r2 = k % DD_, i = r2/56, j = r2%56;
    float cnt = (float)counter[0];
    covTr[k] = covIn[k]/cnt - muTrn[c*56+i]*muTrn[c*56+j];
  }
}

// Coupled Newton-Schulz via fp16-split MFMA.
// which==0 -> sqrt(covTr) into Sout ; which==1 -> invsqrt(covTest) into Zout
__global__ __launch_bounds__(256) void k_ns(const float* __restrict__ covTr, const float* __restrict__ covTest,
                                            float* __restrict__ Sout, float* __restrict__ Zout) {
  __shared__ __align__(16) _Float16 mats[6][64][72];  // Yh,Yl,Zh,Zl,Th,Tl
  __shared__ float red[4];
  int tid = threadIdx.x;
  int which = blockIdx.x & 1, c = blockIdx.x >> 1;
  const float4* Ain4 = (const float4*)((which ? covTest : covTr) + (size_t)c * DD_);

  typedef _Float16 (*mat_t)[72];
  mat_t Yh = mats[0], Yl = mats[1], Zh = mats[2], Zl = mats[3], Th = mats[4], Tl = mats[5];

  // Frobenius norm pass (global reads only)
  float ss = 0.f;
  for (int i4 = tid; i4 < 784; i4 += 256) {
    float4 v = Ain4[i4];
    ss += v.x*v.x + v.y*v.y + v.z*v.z + v.w*v.w;
  }
  // zero all matrices (padding must be 0)
  { unsigned* z = (unsigned*)mats; for (int i = tid; i < 13824; i += 256) z[i] = 0u; }
  #pragma unroll
  for (int off = 32; off > 0; off >>= 1) ss += __shfl_down(ss, off, 64);
  if ((tid & 63) == 0) red[tid >> 6] = ss;
  __syncthreads();
  float s = sqrtf(red[0] + red[1] + red[2] + red[3]);
  float inv = 1.f / s;

  // Y0 = A/s (split), Z0 = I
  for (int i4 = tid; i4 < 784; i4 += 256) {
    float4 v = Ain4[i4];
    int r = i4 / 14, cgx = (i4 % 14) * 4;
    float f0 = v.x*inv, f1 = v.y*inv, f2 = v.z*inv, f3 = v.w*inv;
    v4h hh, ll;
    hh.x = (_Float16)f0; ll.x = (_Float16)(f0 - (float)hh.x);
    hh.y = (_Float16)f1; ll.y = (_Float16)(f1 - (float)hh.y);
    hh.z = (_Float16)f2; ll.z = (_Float16)(f2 - (float)hh.z);
    hh.w = (_Float16)f3; ll.w = (_Float16)(f3 - (float)hh.w);
    *(v4h*)&Yh[r][cgx] = hh;
    *(v4h*)&Yl[r][cgx] = ll;
  }
  if (tid < 56) Zh[tid][tid] = (_Float16)1.0f;
  __syncthreads();

  int lane = tid & 63, w = tid >> 6, lr = lane & 15, lq = lane >> 4;
  v4f zero4 = {0.f, 0.f, 0.f, 0.f};
  float rs = sqrtf(s);
  float fac = which ? (1.f/rs) : rs;
  float* outp = (which ? Zout : Sout) + (size_t)c*DD_;

  for (int it = 0; it < NS_ITERS; ++it) {
    // T = 1.5I - 0.5 * Z@Y
    v4f accW[4] = {zero4, zero4, zero4, zero4};
    mm_split_h(Zh, Zl, Yh, Yl, w, lr, lq, accW);
    v4f Tv[4];
    #pragma unroll
    for (int jt = 0; jt < 4; ++jt) {
      #pragma unroll
      for (int e = 0; e < 4; ++e) {
        float dv = (16*w + 4*lq + e == 16*jt + lr) ? 1.5f : 0.f;
        Tv[jt][e] = dv - 0.5f*accW[jt][e];
      }
    }
    store_split_h(Th, Tl, w, lr, lq, Tv);
    __syncthreads();
    if (it == NS_ITERS - 1) {
      v4f accF[4] = {zero4, zero4, zero4, zero4};
      if (which == 0) mm_split_h(Yh, Yl, Th, Tl, w, lr, lq, accF);  // Y' = Y@T
      else            mm_split_h(Th, Tl, Zh, Zl, w, lr, lq, accF);  // Z' = T@Z
      #pragma unroll
      for (int jt = 0; jt < 4; ++jt) {
        #pragma unroll
        for (int e = 0; e < 4; ++e) {
          int i = 16*w + 4*lq + e, j = 16*jt + lr;
          if (i < 56 && j < 56) outp[i*56 + j] = accF[jt][e] * fac;
        }
      }
    } else {
      v4f accY[4] = {zero4, zero4, zero4, zero4};
      v4f accZ[4] = {zero4, zero4, zero4, zero4};
      mm_split_h(Yh, Yl, Th, Tl, w, lr, lq, accY);   // Y' = Y@T
      mm_split_h(Th, Tl, Zh, Zl, w, lr, lq, accZ);   // Z' = T@Z
      __syncthreads();
      store_split_h(Yh, Yl, w, lr, lq, accY);
      store_split_h(Zh, Zl, w, lr, lq, accZ);
      __syncthreads();
    }
  }
}

// Tm[c] = Zi[c] @ S[c]  via fp16-split MFMA
__global__ __launch_bounds__(256) void k_tmap(const float* __restrict__ Zi, const float* __restrict__ Sm,
                                              float* __restrict__ Tm) {
  __shared__ __align__(16) _Float16 mats[4][64][72];  // Ah,Al (Zi), Bh,Bl (S)
  int c = blockIdx.x, tid = threadIdx.x;
  typedef _Float16 (*mat_t)[72];
  mat_t Ah = mats[0], Al = mats[1], Bh = mats[2], Bl = mats[3];
  { unsigned* z = (unsigned*)mats; for (int i = tid; i < 9216; i += 256) z[i] = 0u; }
  __syncthreads();
  const float4* Z4 = (const float4*)(Zi + (size_t)c*DD_);
  const float4* S4 = (const float4*)(Sm + (size_t)c*DD_);
  for (int i4 = tid; i4 < 784; i4 += 256) {
    int r = i4 / 14, cgx = (i4 % 14) * 4;
    float4 v = Z4[i4];
    v4h hh, ll;
    hh.x = (_Float16)v.x; ll.x = (_Float16)(v.x - (float)hh.x);
    hh.y = (_Float16)v.y; ll.y = (_Float16)(v.y - (float)hh.y);
    hh.z = (_Float16)v.z; ll.z = (_Float16)(v.z - (float)hh.z);
    hh.w = (_Float16)v.w; ll.w = (_Float16)(v.w - (float)hh.w);
    *(v4h*)&Ah[r][cgx] = hh;
    *(v4h*)&Al[r][cgx] = ll;
    v = S4[i4];
    hh.x = (_Float16)v.x; ll.x = (_Float16)(v.x - (float)hh.x);
    hh.y = (_Float16)v.y; ll.y = (_Float16)(v.y - (float)hh.y);
    hh.z = (_Float16)v.z; ll.z = (_Float16)(v.z - (float)hh.z);
    hh.w = (_Float16)v.w; ll.w = (_Float16)(v.w - (float)hh.w);
    *(v4h*)&Bh[r][cgx] = hh;
    *(v4h*)&Bl[r][cgx] = ll;
  }
  __syncthreads();
  int lane = tid & 63, w = tid >> 6, lr = lane & 15, lq = lane >> 4;
  v4f zero4 = {0.f, 0.f, 0.f, 0.f};
  v4f acc[4] = {zero4, zero4, zero4, zero4};
  mm_split_h(Ah, Al, Bh, Bl, w, lr, lq, acc);
  float* op = Tm + (size_t)c*DD_;
  #pragma unroll
  for (int jt = 0; jt < 4; ++jt) {
    #pragma unroll
    for (int e = 0; e < 4; ++e) {
      int i = 16*w + 4*lq + e, j = 16*jt + lr;
      if (i < 56 && j < 56) op[i*56 + j] = acc[jt][e];
    }
  }
}

// Per-(c,n) 56x56 tile: Y = (X - muT) @ T + muTrain via fp16 MFMA, fp32 accum.
__global__ __launch_bounds__(256) void k_apply(const float* __restrict__ in, const float* __restrict__ muT,
                                               const float* __restrict__ Tmp, const float* __restrict__ muTrain,
                                               float* __restrict__ out, int stage) {
  int b = blockIdx.x;
  int c = b >> 6, n = b & 63;
  __shared__ __align__(16) char lds[18432];
  _Float16 (*Abf)[72] = (_Float16(*)[72])lds;          // centered rows fp16 [m][k]
  _Float16 (*Tt)[72]  = (_Float16(*)[72])(lds + 9216); // T^T fp16 [f][k]
  float (*Y)[67] = (float(*)[67])lds;                  // epilogue overlay (17152 B)
  __shared__ float smu[64], smt[64];
  int tid = threadIdx.x;
  if (tid < 64) {
    smu[tid] = muT[c*64 + tid];
    smt[tid] = (tid < 56) ? muTrain[c*56 + tid] : 0.f;
  }
  {
    unsigned* za = (unsigned*)lds;   // zero both tiles (K padding must be 0)
    for (int i = tid; i < 2*2304; i += 256) za[i] = 0u;
  }
  __syncthreads();
  const float4* p4 = (const float4*)(in + (size_t)c*PL_ + (size_t)n*3136);
  const float4* t4 = (const float4*)(Tmp + (size_t)c*DD_);
  for (int i = tid; i < 784; i += 256) {
    float4 v = p4[i];
    int row = i / 14, cgx = (i % 14) * 4;
    v4h pk;
    pk.x = (_Float16)(v.x - smu[cgx+0]);
    pk.y = (_Float16)(v.y - smu[cgx+1]);
    pk.z = (_Float16)(v.z - smu[cgx+2]);
    pk.w = (_Float16)(v.w - smu[cgx+3]);
    *(v4h*)&Abf[row][cgx] = pk;
    float4 t = t4[i];
    Tt[cgx+0][row] = (_Float16)t.x;
    Tt[cgx+1][row] = (_Float16)t.y;
    Tt[cgx+2][row] = (_Float16)t.z;
    Tt[cgx+3][row] = (_Float16)t.w;
  }
  __syncthreads();
  int l = tid & 63, w = tid >> 6;
  int lr = l & 15, lq = l >> 4;
  v4f zero4 = {0.f, 0.f, 0.f, 0.f};
  v4f acc[4];
  #pragma unroll
  for (int j = 0; j < 4; ++j) acc[j] = zero4;
  #pragma unroll
  for (int s = 0; s < 2; ++s) {
    int kb = 32*s + 8*lq;
    v8h a = *(const v8h*)&Abf[16*w + lr][kb];
    #pragma unroll
    for (int j = 0; j < 4; ++j) {
      v8h bb = *(const v8h*)&Tt[16*j + lr][kb];
      acc[j] = __builtin_amdgcn_mfma_f32_16x16x32_f16(a, bb, acc[j], 0, 0, 0);
    }
  }
  __syncthreads();   // done reading tiles; overlay Y
  #pragma unroll
  for (int j = 0; j < 4; ++j) {
    #pragma unroll
    for (int e = 0; e < 4; ++e) {
      int r = 16*w + 4*lq + e, cc = 16*j + lr;
      Y[r][cc] = acc[j][e] + smt[cc];
    }
  }
  __syncthreads();
  float4* op4 = (float4*)(out + (size_t)c*PL_ + (size_t)n*3136);
  if (stage == 1) {
    for (int i4 = tid; i4 < 784; i4 += 256) {
      int h = i4 / 14, w4 = (i4 % 14) * 4;
      float4 o;
      o.x = Y[w4+0][h]; o.y = Y[w4+1][h]; o.z = Y[w4+2][h]; o.w = Y[w4+3][h];
      op4[i4] = o;
    }
  } else {
    for (int i4 = tid; i4 < 784; i4 += 256) {
      int h = i4 / 14, w4 = (i4 % 14) * 4;
      float4 o;
      o.x = Y[h][w4+0]; o.y = Y[h][w4+1]; o.z = Y[h][w4+2]; o.w = Y[h][w4+3];
      op4[i4] = o;
    }
  }
}

// A2 (c, n, h, w) -> out (n, h, w, c)
__global__ __launch_bounds__(256) void k_tout(const float* __restrict__ A2, float* __restrict__ out) {
  int b = blockIdx.x;
  int cchunk = b & 3, nh = b >> 2;
  int c0 = cchunk * 64;
  __shared__ float t[64][57];
  int tid = threadIdx.x;
  const float* Ap = A2 + (size_t)c0*PL_ + (size_t)nh*56;
  for (int i = tid; i < 64*56; i += 256) {
    int cc = i / 56, w = i % 56;
    t[cc][w] = Ap[(size_t)cc*PL_ + w];
  }
  __syncthreads();
  float* op = out + (size_t)nh*56*256 + c0;
  for (int i = tid; i < 56*64; i += 256) {
    int w = i >> 6, cc = i & 63;
    op[(size_t)w*256 + cc] = t[cc][w];
  }
}

extern "C" void kernel_launch(void* const* d_in, const int* in_sizes, int n_in,
                              void* d_out, int out_size, void* d_ws, size_t ws_size,
                              hipStream_t stream) {
  (void)in_sizes; (void)n_in; (void)out_size;
  const float* x    = (const float*)d_in[0];
  const float* covH = (const float*)d_in[1];
  const float* muH  = (const float*)d_in[2];
  const float* covW = (const float*)d_in[3];
  const float* muW  = (const float*)d_in[4];
  const int*   cnt  = (const int*)d_in[5];
  float* out = (float*)d_out;

  char* ws = (char*)d_ws;
  size_t off = 0;
  auto alloc = [&](size_t nfloats) {
    float* p = (float*)(ws + off);
    off += ((nfloats*sizeof(float) + 255) / 256) * 256;
    return p;
  };
  float* A       = alloc((size_t)C_ * PL_);
  float* covPart = alloc((size_t)8 * C_ * DD_);
  float* muPart  = alloc((size_t)8 * C_ * 64);
  float* covTest = alloc((size_t)C_ * DD_);
  float* covTr   = alloc((size_t)C_ * DD_);
  float* Sm      = alloc((size_t)C_ * DD_);
  float* Zim     = alloc((size_t)C_ * DD_);
  float* Tm      = alloc((size_t)C_ * DD_);
  float* muT     = alloc((size_t)C_ * 64);
  if (off > ws_size) return;

  dim3 blk(256);
  const int finGrid = (2*C_*DD_ + 255)/256;

  k_tin<<<dim3(14336), blk, 0, stream>>>(x, A);

  // ---- stage 1 (H axis) ----
  k_stats   <<<dim3(2048),  blk, 0, stream>>>(A, muPart, covPart);
  k_mured   <<<dim3(64),    blk, 0, stream>>>(muPart, muT);
  k_finalize<<<dim3(finGrid), blk, 0, stream>>>(covPart, muT, covH, muH, cnt, covTest, covTr);
  k_ns      <<<dim3(512),   blk, 0, stream>>>(covTr, covTest, Sm, Zim);
  k_tmap    <<<dim3(256),   blk, 0, stream>>>(Zim, Sm, Tm);
  k_apply   <<<dim3(16384), blk, 0, stream>>>(A, muT, Tm, muH, out, 1);

  // ---- stage 2 (W axis) ----
  k_stats   <<<dim3(2048),  blk, 0, stream>>>(out, muPart, covPart);
  k_mured   <<<dim3(64),    blk, 0, stream>>>(muPart, muT);
  k_finalize<<<dim3(finGrid), blk, 0, stream>>>(covPart, muT, covW, muW, cnt, covTest, covTr);
  k_ns      <<<dim3(512),   blk, 0, stream>>>(covTr, covTest, Sm, Zim);
  k_tmap    <<<dim3(256),   blk, 0, stream>>>(Zim, Sm, Tm);
  k_apply   <<<dim3(16384), blk, 0, stream>>>(out, muT, Tm, muW, A, 2);

  k_tout<<<dim3(14336), blk, 0, stream>>>(A, out);
}

// Round 5
// 618.713 us; speedup vs baseline: 2.2445x; 1.0628x over previous
//
#include <hip/hip_runtime.h>

#define C_ 256
#define D_ 56
#define N_ 64
#define M_ 3584     // rows per channel (N*56), same both stages since H==W
#define DD_ 3136    // 56*56
#define PL_ 200704  // per-channel plane = M_*56
#define NS_ITERS 16

typedef __attribute__((ext_vector_type(8))) short v8s;
typedef __attribute__((ext_vector_type(8))) _Float16 v8h;
typedef __attribute__((ext_vector_type(4))) _Float16 v4h;
typedef __attribute__((ext_vector_type(4))) float v4f;

__device__ __forceinline__ unsigned short f2bf(float f) {
  union { float f; unsigned u; } x; x.f = f;
  unsigned r = x.u + 0x7FFFu + ((x.u >> 16) & 1u);
  return (unsigned short)(r >> 16);
}
__device__ __forceinline__ float bf2f(unsigned short h) {
  union { unsigned u; float f; } x; x.u = ((unsigned)h) << 16;
  return x.f;
}

// x (N,H,W,C) -> A (C, n*56+w, h)   [float4 both sides]
__global__ __launch_bounds__(256) void k_tin(const float* __restrict__ x, float* __restrict__ A) {
  int b = blockIdx.x;
  int cchunk = b & 3, nw = b >> 2;
  int n = nw / 56, w = nw % 56;
  int c0 = cchunk * 64;
  __shared__ float t[56][65];
  int tid = threadIdx.x;
  const float4* xp4 = (const float4*)(x + ((size_t)n*3136 + w)*256 + c0);
  for (int i4 = tid; i4 < 896; i4 += 256) {     // 56 h x 16 cgroups
    int h = i4 >> 4, cg = i4 & 15;
    float4 v = xp4[(size_t)h*3584 + cg];
    t[h][4*cg+0] = v.x; t[h][4*cg+1] = v.y; t[h][4*cg+2] = v.z; t[h][4*cg+3] = v.w;
  }
  __syncthreads();
  float* Ap = A + (size_t)c0*PL_ + (size_t)nw*56;
  for (int i4 = tid; i4 < 896; i4 += 256) {     // 64 cc x 14 hgroups
    int cc = i4 / 14, hg = (i4 % 14) * 4;
    float4 o;
    o.x = t[hg+0][cc]; o.y = t[hg+1][cc]; o.z = t[hg+2][cc]; o.w = t[hg+3][cc];
    *(float4*)&Ap[(size_t)cc*PL_ + hg] = o;
  }
}

// ---------- fp16-split MFMA helpers (2-way split: ~2^-22 effective precision) ----------
// acc[jt] += C where C[i][j] = sum_k (Ah+Al)[i][k] * (Bh+Bl)[j][k]  (Al*Bl dropped)
// i = 16*w + 4*lq + e, j = 16*jt + lr
__device__ __forceinline__ void mm_split_h(const _Float16 (*Ah)[72], const _Float16 (*Al)[72],
                                           const _Float16 (*Bh)[72], const _Float16 (*Bl)[72],
                                           int w, int lr, int lq, v4f (&acc)[4]) {
  v8h ah[2], al[2], bh[4][2], bl[4][2];
  #pragma unroll
  for (int s = 0; s < 2; ++s) {
    int kb = 32*s + 8*lq;
    ah[s] = *(const v8h*)&Ah[16*w + lr][kb];
    al[s] = *(const v8h*)&Al[16*w + lr][kb];
    #pragma unroll
    for (int jt = 0; jt < 4; ++jt) {
      bh[jt][s] = *(const v8h*)&Bh[16*jt + lr][kb];
      bl[jt][s] = *(const v8h*)&Bl[16*jt + lr][kb];
    }
  }
  #pragma unroll
  for (int jt = 0; jt < 4; ++jt) {
    #pragma unroll
    for (int s = 0; s < 2; ++s) {
      acc[jt] = __builtin_amdgcn_mfma_f32_16x16x32_f16(ah[s], bh[jt][s], acc[jt], 0, 0, 0);
      acc[jt] = __builtin_amdgcn_mfma_f32_16x16x32_f16(ah[s], bl[jt][s], acc[jt], 0, 0, 0);
      acc[jt] = __builtin_amdgcn_mfma_f32_16x16x32_f16(al[s], bh[jt][s], acc[jt], 0, 0, 0);
    }
  }
}

__device__ __forceinline__ void store_split_h(_Float16 (*H)[72], _Float16 (*L)[72],
                                              int w, int lr, int lq, const v4f (&val)[4]) {
  #pragma unroll
  for (int jt = 0; jt < 4; ++jt) {
    #pragma unroll
    for (int e = 0; e < 4; ++e) {
      int i = 16*w + 4*lq + e, j = 16*jt + lr;
      float v = val[jt][e];
      _Float16 h = (_Float16)v;
      H[i][j] = h;
      L[i][j] = (_Float16)(v - (float)h);
    }
  }
}

// Fused: raw column-sum (fp32 exact, in-register) + raw second moment via split-bf16 MFMA.
// (bf16-split is fine here: cov error gets divided by M=3584 -> ~1e-7 abs)
// in: (C, 3584, 56). out: muPart[s][c][64], covPart[(s*C+c)][56*56]
__global__ __launch_bounds__(256) void k_stats(const float* __restrict__ in,
                                               float* __restrict__ muPart,
                                               float* __restrict__ covPart) {
  int b = blockIdx.x;
  int c = b >> 3, s = b & 7;
  const float* p = in + (size_t)c*PL_ + (size_t)(s*448)*56;
  __shared__ __align__(16) char lds[18432];
  unsigned short (*At)[72]  = (unsigned short(*)[72])lds;          // Ah transposed [d][m]
  unsigned short (*Alt)[72] = (unsigned short(*)[72])(lds + 9216); // Al transposed [d][m]
  float (*Qbuf)[66] = (float(*)[66])lds;                           // epilogue overlay
  float (*red2)[60] = (float(*)[60])lds;                           // mu-reduction overlay
  int tid = threadIdx.x;
  int cg = tid % 14, rg = tid / 14;     // column-group / row-group (valid tid<224)
  bool act = tid < 224;
  float4 colsum = make_float4(0.f, 0.f, 0.f, 0.f);

  int l = tid & 63, w = tid >> 6;
  int lr = l & 15, lq = l >> 4;
  v4f zero4 = {0.f, 0.f, 0.f, 0.f};
  v4f accP[4], accQ[4];
  #pragma unroll
  for (int j = 0; j < 4; ++j) { accP[j] = zero4; accQ[j] = zero4; }

  for (int ch = 0; ch < 7; ++ch) {
    __syncthreads();
    const float4* p4 = (const float4*)(p + ch*64*56);
    if (act) {
      int c4 = cg * 4;
      #pragma unroll
      for (int u = 0; u < 4; ++u) {
        int m = u*16 + rg;
        float4 v = p4[m*14 + cg];
        colsum.x += v.x; colsum.y += v.y; colsum.z += v.z; colsum.w += v.w;
        unsigned short h;
        h = f2bf(v.x); At[c4+0][m] = h; Alt[c4+0][m] = f2bf(v.x - bf2f(h));
        h = f2bf(v.y); At[c4+1][m] = h; Alt[c4+1][m] = f2bf(v.y - bf2f(h));
        h = f2bf(v.z); At[c4+2][m] = h; Alt[c4+2][m] = f2bf(v.z - bf2f(h));
        h = f2bf(v.w); At[c4+3][m] = h; Alt[c4+3][m] = f2bf(v.w - bf2f(h));
      }
    }
    __syncthreads();
    #pragma unroll
    for (int s2 = 0; s2 < 2; ++s2) {
      int kb = 32*s2 + 8*lq;
      v8s a = *(const v8s*)&At[16*w + lr][kb];
      #pragma unroll
      for (int j = 0; j < 4; ++j) {
        v8s bh = *(const v8s*)&At[16*j + lr][kb];
        v8s bl = *(const v8s*)&Alt[16*j + lr][kb];
        accP[j] = __builtin_amdgcn_mfma_f32_16x16x32_bf16(a, bh, accP[j], 0, 0, 0);
        accQ[j] = __builtin_amdgcn_mfma_f32_16x16x32_bf16(a, bl, accQ[j], 0, 0, 0);
      }
    }
  }

  // ---- mu reduction (overlay on At region; MFMA reads are done) ----
  __syncthreads();
  if (act) *(float4*)&red2[rg][cg*4] = colsum;
  __syncthreads();
  if (tid < 64) {
    float m = 0.f;
    if (tid < 56) {
      #pragma unroll
      for (int r = 0; r < 16; ++r) m += red2[r][tid];
    }
    muPart[((size_t)s*C_ + c)*64 + tid] = m;   // cols 56..63 = 0
  }
  __syncthreads();

  // ---- epilogue: S = P + Q + Q^T ----
  #pragma unroll
  for (int j = 0; j < 4; ++j) {
    #pragma unroll
    for (int e = 0; e < 4; ++e) {
      int r = 16*w + 4*lq + e, cc = 16*j + lr;
      Qbuf[r][cc] = accQ[j][e];
    }
  }
  __syncthreads();
  float* op = covPart + ((size_t)s*C_ + c)*DD_;
  #pragma unroll
  for (int j = 0; j < 4; ++j) {
    #pragma unroll
    for (int e = 0; e < 4; ++e) {
      int r = 16*w + 4*lq + e, cc = 16*j + lr;
      if (r < 56 && cc < 56) op[r*56 + cc] = accP[j][e] + accQ[j][e] + Qbuf[cc][r];
    }
  }
}

__global__ __launch_bounds__(256) void k_mured(const float* __restrict__ muPart, float* __restrict__ muT) {
  int idx = blockIdx.x*256 + threadIdx.x;
  if (idx >= C_*64) return;
  int c = idx >> 6, lane = idx & 63;
  float s = 0.f;
  for (int p = 0; p < 8; ++p) s += muPart[((size_t)p*C_ + c)*64 + lane];
  muT[idx] = s * (1.0f/M_);
}

// test cov (from parts + mu, jittered) AND train cov (from covIn + muTrain + counter)
__global__ __launch_bounds__(256) void k_finalize(const float* __restrict__ covPart, const float* __restrict__ muT,
                                                  const float* __restrict__ covIn, const float* __restrict__ muTrn,
                                                  const int* __restrict__ counter,
                                                  float* __restrict__ covTest, float* __restrict__ covTr) {
  int idx = blockIdx.x*256 + threadIdx.x;
  const int total = C_*DD_;
  if (idx < total) {
    int c = idx / DD_, r2 = idx % DD_, i = r2/56, j = r2%56;
    float ssum = 0.f;
    for (int s = 0; s < 8; ++s) ssum += covPart[((size_t)s*C_ + c)*DD_ + r2];
    float v = ssum*(1.0f/M_) - muT[c*64+i]*muT[c*64+j];
    if (i == j) v *= 1.001f;
    covTest[idx] = v;
  } else if (idx < 2*total) {
    int k = idx - total;
    int c = k / DD_, r2 = k % DD_, i = r2/56, j = r2%56;
    float cnt = (float)counter[0];
    covTr[k] = covIn[k]/cnt - muTrn[c*56+i]*muTrn[c*56+j];
  }
}

// Coupled Newton-Schulz via fp16-split MFMA.
// which==0 -> sqrt(covTr) into Sout ; which==1 -> invsqrt(covTest) into Zout
__global__ __launch_bounds__(256) void k_ns(const float* __restrict__ covTr, const float* __restrict__ covTest,
                                            float* __restrict__ Sout, float* __restrict__ Zout) {
  __shared__ __align__(16) _Float16 mats[6][64][72];  // Yh,Yl,Zh,Zl,Th,Tl
  __shared__ float red[4];
  int tid = threadIdx.x;
  int which = blockIdx.x & 1, c = blockIdx.x >> 1;
  const float4* Ain4 = (const float4*)((which ? covTest : covTr) + (size_t)c * DD_);

  typedef _Float16 (*mat_t)[72];
  mat_t Yh = mats[0], Yl = mats[1], Zh = mats[2], Zl = mats[3], Th = mats[4], Tl = mats[5];

  // Frobenius norm pass (global reads only)
  float ss = 0.f;
  for (int i4 = tid; i4 < 784; i4 += 256) {
    float4 v = Ain4[i4];
    ss += v.x*v.x + v.y*v.y + v.z*v.z + v.w*v.w;
  }
  // zero all matrices (padding must be 0)
  { unsigned* z = (unsigned*)mats; for (int i = tid; i < 13824; i += 256) z[i] = 0u; }
  #pragma unroll
  for (int off = 32; off > 0; off >>= 1) ss += __shfl_down(ss, off, 64);
  if ((tid & 63) == 0) red[tid >> 6] = ss;
  __syncthreads();
  float s = sqrtf(red[0] + red[1] + red[2] + red[3]);
  float inv = 1.f / s;

  // Y0 = A/s (split), Z0 = I
  for (int i4 = tid; i4 < 784; i4 += 256) {
    float4 v = Ain4[i4];
    int r = i4 / 14, cgx = (i4 % 14) * 4;
    float f0 = v.x*inv, f1 = v.y*inv, f2 = v.z*inv, f3 = v.w*inv;
    v4h hh, ll;
    hh.x = (_Float16)f0; ll.x = (_Float16)(f0 - (float)hh.x);
    hh.y = (_Float16)f1; ll.y = (_Float16)(f1 - (float)hh.y);
    hh.z = (_Float16)f2; ll.z = (_Float16)(f2 - (float)hh.z);
    hh.w = (_Float16)f3; ll.w = (_Float16)(f3 - (float)hh.w);
    *(v4h*)&Yh[r][cgx] = hh;
    *(v4h*)&Yl[r][cgx] = ll;
  }
  if (tid < 56) Zh[tid][tid] = (_Float16)1.0f;
  __syncthreads();

  int lane = tid & 63, w = tid >> 6, lr = lane & 15, lq = lane >> 4;
  v4f zero4 = {0.f, 0.f, 0.f, 0.f};
  float rs = sqrtf(s);
  float fac = which ? (1.f/rs) : rs;
  float* outp = (which ? Zout : Sout) + (size_t)c*DD_;

  for (int it = 0; it < NS_ITERS; ++it) {
    // T = 1.5I - 0.5 * Z@Y
    v4f accW[4] = {zero4, zero4, zero4, zero4};
    mm_split_h(Zh, Zl, Yh, Yl, w, lr, lq, accW);
    v4f Tv[4];
    #pragma unroll
    for (int jt = 0; jt < 4; ++jt) {
      #pragma unroll
      for (int e = 0; e < 4; ++e) {
        float dv = (16*w + 4*lq + e == 16*jt + lr) ? 1.5f : 0.f;
        Tv[jt][e] = dv - 0.5f*accW[jt][e];
      }
    }
    store_split_h(Th, Tl, w, lr, lq, Tv);
    __syncthreads();
    if (it == NS_ITERS - 1) {
      v4f accF[4] = {zero4, zero4, zero4, zero4};
      if (which == 0) mm_split_h(Yh, Yl, Th, Tl, w, lr, lq, accF);  // Y' = Y@T
      else            mm_split_h(Th, Tl, Zh, Zl, w, lr, lq, accF);  // Z' = T@Z
      #pragma unroll
      for (int jt = 0; jt < 4; ++jt) {
        #pragma unroll
        for (int e = 0; e < 4; ++e) {
          int i = 16*w + 4*lq + e, j = 16*jt + lr;
          if (i < 56 && j < 56) outp[i*56 + j] = accF[jt][e] * fac;
        }
      }
    } else {
      v4f accY[4] = {zero4, zero4, zero4, zero4};
      v4f accZ[4] = {zero4, zero4, zero4, zero4};
      mm_split_h(Yh, Yl, Th, Tl, w, lr, lq, accY);   // Y' = Y@T
      mm_split_h(Th, Tl, Zh, Zl, w, lr, lq, accZ);   // Z' = T@Z
      __syncthreads();
      store_split_h(Yh, Yl, w, lr, lq, accY);
      store_split_h(Zh, Zl, w, lr, lq, accZ);
      __syncthreads();
    }
  }
}

// Tm[c] = Zi[c] @ S[c]  via fp16-split MFMA
__global__ __launch_bounds__(256) void k_tmap(const float* __restrict__ Zi, const float* __restrict__ Sm,
                                              float* __restrict__ Tm) {
  __shared__ __align__(16) _Float16 mats[4][64][72];  // Ah,Al (Zi), Bh,Bl (S)
  int c = blockIdx.x, tid = threadIdx.x;
  typedef _Float16 (*mat_t)[72];
  mat_t Ah = mats[0], Al = mats[1], Bh = mats[2], Bl = mats[3];
  { unsigned* z = (unsigned*)mats; for (int i = tid; i < 9216; i += 256) z[i] = 0u; }
  __syncthreads();
  const float4* Z4 = (const float4*)(Zi + (size_t)c*DD_);
  const float4* S4 = (const float4*)(Sm + (size_t)c*DD_);
  for (int i4 = tid; i4 < 784; i4 += 256) {
    int r = i4 / 14, cgx = (i4 % 14) * 4;
    float4 v = Z4[i4];
    v4h hh, ll;
    hh.x = (_Float16)v.x; ll.x = (_Float16)(v.x - (float)hh.x);
    hh.y = (_Float16)v.y; ll.y = (_Float16)(v.y - (float)hh.y);
    hh.z = (_Float16)v.z; ll.z = (_Float16)(v.z - (float)hh.z);
    hh.w = (_Float16)v.w; ll.w = (_Float16)(v.w - (float)hh.w);
    *(v4h*)&Ah[r][cgx] = hh;
    *(v4h*)&Al[r][cgx] = ll;
    v = S4[i4];
    hh.x = (_Float16)v.x; ll.x = (_Float16)(v.x - (float)hh.x);
    hh.y = (_Float16)v.y; ll.y = (_Float16)(v.y - (float)hh.y);
    hh.z = (_Float16)v.z; ll.z = (_Float16)(v.z - (float)hh.z);
    hh.w = (_Float16)v.w; ll.w = (_Float16)(v.w - (float)hh.w);
    *(v4h*)&Bh[r][cgx] = hh;
    *(v4h*)&Bl[r][cgx] = ll;
  }
  __syncthreads();
  int lane = tid & 63, w = tid >> 6, lr = lane & 15, lq = lane >> 4;
  v4f zero4 = {0.f, 0.f, 0.f, 0.f};
  v4f acc[4] = {zero4, zero4, zero4, zero4};
  mm_split_h(Ah, Al, Bh, Bl, w, lr, lq, acc);
  float* op = Tm + (size_t)c*DD_;
  #pragma unroll
  for (int jt = 0; jt < 4; ++jt) {
    #pragma unroll
    for (int e = 0; e < 4; ++e) {
      int i = 16*w + 4*lq + e, j = 16*jt + lr;
      if (i < 56 && j < 56) op[i*56 + j] = acc[jt][e];
    }
  }
}

// Per-(c,n) 56x56 tile: Y = (X - muT) @ T + muTrain via fp16 MFMA, fp32 accum.
__global__ __launch_bounds__(256) void k_apply(const float* __restrict__ in, const float* __restrict__ muT,
                                               const float* __restrict__ Tmp, const float* __restrict__ muTrain,
                                               float* __restrict__ out, int stage) {
  int b = blockIdx.x;
  int c = b >> 6, n = b & 63;
  __shared__ __align__(16) char lds[18432];
  _Float16 (*Abf)[72] = (_Float16(*)[72])lds;          // centered rows fp16 [m][k]
  _Float16 (*Tt)[72]  = (_Float16(*)[72])(lds + 9216); // T^T fp16 [f][k]
  float (*Y)[67] = (float(*)[67])lds;                  // epilogue overlay (17152 B)
  __shared__ float smu[64], smt[64];
  int tid = threadIdx.x;
  if (tid < 64) {
    smu[tid] = muT[c*64 + tid];
    smt[tid] = (tid < 56) ? muTrain[c*56 + tid] : 0.f;
  }
  // zero only the K-pad (cols 56..63) of both operand tiles; garbage elsewhere
  // is confined to unused output rows/cols (never written back).
  if (tid < 128) {
    int row = tid & 63;
    _Float16 (*Mz)[72] = (tid < 64) ? Abf : Tt;
    *(float4*)&Mz[row][56] = make_float4(0.f, 0.f, 0.f, 0.f);
  }
  __syncthreads();
  const float4* p4 = (const float4*)(in + (size_t)c*PL_ + (size_t)n*3136);
  const float4* t4 = (const float4*)(Tmp + (size_t)c*DD_);
  for (int i = tid; i < 784; i += 256) {
    float4 v = p4[i];
    int row = i / 14, cgx = (i % 14) * 4;
    v4h pk;
    pk.x = (_Float16)(v.x - smu[cgx+0]);
    pk.y = (_Float16)(v.y - smu[cgx+1]);
    pk.z = (_Float16)(v.z - smu[cgx+2]);
    pk.w = (_Float16)(v.w - smu[cgx+3]);
    *(v4h*)&Abf[row][cgx] = pk;
    float4 t = t4[i];
    Tt[cgx+0][row] = (_Float16)t.x;
    Tt[cgx+1][row] = (_Float16)t.y;
    Tt[cgx+2][row] = (_Float16)t.z;
    Tt[cgx+3][row] = (_Float16)t.w;
  }
  __syncthreads();
  int l = tid & 63, w = tid >> 6;
  int lr = l & 15, lq = l >> 4;
  v4f zero4 = {0.f, 0.f, 0.f, 0.f};
  v4f acc[4];
  #pragma unroll
  for (int j = 0; j < 4; ++j) acc[j] = zero4;
  #pragma unroll
  for (int s = 0; s < 2; ++s) {
    int kb = 32*s + 8*lq;
    v8h a = *(const v8h*)&Abf[16*w + lr][kb];
    #pragma unroll
    for (int j = 0; j < 4; ++j) {
      v8h bb = *(const v8h*)&Tt[16*j + lr][kb];
      acc[j] = __builtin_amdgcn_mfma_f32_16x16x32_f16(a, bb, acc[j], 0, 0, 0);
    }
  }
  __syncthreads();   // done reading tiles; overlay Y
  #pragma unroll
  for (int j = 0; j < 4; ++j) {
    #pragma unroll
    for (int e = 0; e < 4; ++e) {
      int r = 16*w + 4*lq + e, cc = 16*j + lr;
      Y[r][cc] = acc[j][e] + smt[cc];
    }
  }
  __syncthreads();
  float4* op4 = (float4*)(out + (size_t)c*PL_ + (size_t)n*3136);
  if (stage == 1) {
    for (int i4 = tid; i4 < 784; i4 += 256) {
      int h = i4 / 14, w4 = (i4 % 14) * 4;
      float4 o;
      o.x = Y[w4+0][h]; o.y = Y[w4+1][h]; o.z = Y[w4+2][h]; o.w = Y[w4+3][h];
      op4[i4] = o;
    }
  } else {
    for (int i4 = tid; i4 < 784; i4 += 256) {
      int h = i4 / 14, w4 = (i4 % 14) * 4;
      float4 o;
      o.x = Y[h][w4+0]; o.y = Y[h][w4+1]; o.z = Y[h][w4+2]; o.w = Y[h][w4+3];
      op4[i4] = o;
    }
  }
}

// A2 (c, n, h, w) -> out (n, h, w, c)   [float4 both sides]
__global__ __launch_bounds__(256) void k_tout(const float* __restrict__ A2, float* __restrict__ out) {
  int b = blockIdx.x;
  int cchunk = b & 3, nh = b >> 2;
  int c0 = cchunk * 64;
  __shared__ float t[64][57];
  int tid = threadIdx.x;
  const float* Ap = A2 + (size_t)c0*PL_ + (size_t)nh*56;
  for (int i4 = tid; i4 < 896; i4 += 256) {     // 64 cc x 14 wgroups
    int cc = i4 / 14, wg = (i4 % 14) * 4;
    float4 v = *(const float4*)&Ap[(size_t)cc*PL_ + wg];
    t[cc][wg+0] = v.x; t[cc][wg+1] = v.y; t[cc][wg+2] = v.z; t[cc][wg+3] = v.w;
  }
  __syncthreads();
  float4* op4 = (float4*)(out + (size_t)nh*56*256 + c0);
  for (int i4 = tid; i4 < 896; i4 += 256) {     // 56 w x 16 cgroups
    int w = i4 >> 4, cg = i4 & 15;
    float4 o;
    o.x = t[4*cg+0][w]; o.y = t[4*cg+1][w]; o.z = t[4*cg+2][w]; o.w = t[4*cg+3][w];
    op4[(size_t)w*64 + cg] = o;
  }
}

extern "C" void kernel_launch(void* const* d_in, const int* in_sizes, int n_in,
                              void* d_out, int out_size, void* d_ws, size_t ws_size,
                              hipStream_t stream) {
  (void)in_sizes; (void)n_in; (void)out_size;
  const float* x    = (const float*)d_in[0];
  const float* covH = (const float*)d_in[1];
  const float* muH  = (const float*)d_in[2];
  const float* covW = (const float*)d_in[3];
  const float* muW  = (const float*)d_in[4];
  const int*   cnt  = (const int*)d_in[5];
  float* out = (float*)d_out;

  char* ws = (char*)d_ws;
  size_t off = 0;
  auto alloc = [&](size_t nfloats) {
    float* p = (float*)(ws + off);
    off += ((nfloats*sizeof(float) + 255) / 256) * 256;
    return p;
  };
  float* A       = alloc((size_t)C_ * PL_);
  float* covPart = alloc((size_t)8 * C_ * DD_);
  float* muPart  = alloc((size_t)8 * C_ * 64);
  float* covTest = alloc((size_t)C_ * DD_);
  float* covTr   = alloc((size_t)C_ * DD_);
  float* Sm      = alloc((size_t)C_ * DD_);
  float* Zim     = alloc((size_t)C_ * DD_);
  float* Tm      = alloc((size_t)C_ * DD_);
  float* muT     = alloc((size_t)C_ * 64);
  if (off > ws_size) return;

  dim3 blk(256);
  const int finGrid = (2*C_*DD_ + 255)/256;

  k_tin<<<dim3(14336), blk, 0, stream>>>(x, A);

  // ---- stage 1 (H axis) ----
  k_stats   <<<dim3(2048),  blk, 0, stream>>>(A, muPart, covPart);
  k_mured   <<<dim3(64),    blk, 0, stream>>>(muPart, muT);
  k_finalize<<<dim3(finGrid), blk, 0, stream>>>(covPart, muT, covH, muH, cnt, covTest, covTr);
  k_ns      <<<dim3(512),   blk, 0, stream>>>(covTr, covTest, Sm, Zim);
  k_tmap    <<<dim3(256),   blk, 0, stream>>>(Zim, Sm, Tm);
  k_apply   <<<dim3(16384), blk, 0, stream>>>(A, muT, Tm, muH, out, 1);

  // ---- stage 2 (W axis) ----
  k_stats   <<<dim3(2048),  blk, 0, stream>>>(out, muPart, covPart);
  k_mured   <<<dim3(64),    blk, 0, stream>>>(muPart, muT);
  k_finalize<<<dim3(finGrid), blk, 0, stream>>>(covPart, muT, covW, muW, cnt, covTest, covTr);
  k_ns      <<<dim3(512),   blk, 0, stream>>>(covTr, covTest, Sm, Zim);
  k_tmap    <<<dim3(256),   blk, 0, stream>>>(Zim, Sm, Tm);
  k_apply   <<<dim3(16384), blk, 0, stream>>>(out, muT, Tm, muW, A, 2);

  k_tout<<<dim3(14336), blk, 0, stream>>>(A, out);
}